// Round 14
// baseline (125.627 us; speedup 1.0000x reference)
//
#include <hip/hip_runtime.h>
#include <hip/hip_bf16.h>
#include <stdint.h>

#define HIDDEN 1024
#define SEQL   2048
#define NB     2
#define NH     16
#define DH     64
#define MTOT   (NB * SEQL)   // 4096
#define QKVLD  3072          // fused QKV row stride
#define SCALE_Q 0.18033688011112042f   // 0.125 * log2(e)

typedef __bf16 bf16x8 __attribute__((ext_vector_type(8)));
typedef __bf16 bf16x4 __attribute__((ext_vector_type(4)));
typedef float  f32x4  __attribute__((ext_vector_type(4)));
typedef float  f32x16 __attribute__((ext_vector_type(16)));

__device__ __forceinline__ void gload16(const void* g, void* l) {
    __builtin_amdgcn_global_load_lds(
        (const __attribute__((address_space(1))) void*)g,
        (__attribute__((address_space(3))) void*)l, 16, 0, 0);
}
__device__ __forceinline__ float exp2fast(float x) {
    float r;
    asm("v_exp_f32 %0, %1" : "=v"(r) : "v"(x));
    return r;
}
__device__ __forceinline__ unsigned cvtpk(float lo, float hi) {
    unsigned r;
    asm("v_cvt_pk_bf16_f32 %0, %1, %2" : "=v"(r) : "v"(lo), "v"(hi));
    return r;
}
__device__ __forceinline__ void pswap(unsigned& a, unsigned& b) {
    asm volatile("v_permlane32_swap_b32 %0, %1" : "+v"(a), "+v"(b));
}
// counted-vmcnt barriers (T4)
__device__ __forceinline__ void barrier_vm3() {
    asm volatile("s_waitcnt vmcnt(3)" ::: "memory");
    __builtin_amdgcn_s_barrier();
    asm volatile("" ::: "memory");
}
__device__ __forceinline__ void barrier_vm4() {
    asm volatile("s_waitcnt vmcnt(4)" ::: "memory");
    __builtin_amdgcn_s_barrier();
    asm volatile("" ::: "memory");
}

// ---------------------------------------------------------------- fused prep
__global__ void prep(const float* __restrict__ H,
                     const float* __restrict__ Wq, const float* __restrict__ Wk,
                     const float* __restrict__ Wv, const float* __restrict__ Wd,
                     const float* __restrict__ bq, const float* __restrict__ bk,
                     const float* __restrict__ bv,
                     __bf16* __restrict__ Hb, __bf16* __restrict__ Wall,
                     float* __restrict__ bqkv) {
    const int bid = blockIdx.x, tid = threadIdx.x;
    if (bid < 4096) {
        int i = bid * 256 + tid;
        float4 v = reinterpret_cast<const float4*>(H)[i];
        bf16x4 o = { (__bf16)v.x, (__bf16)v.y, (__bf16)v.z, (__bf16)v.w };
        reinterpret_cast<bf16x4*>(Hb)[i] = o;
    } else if (bid < 8192) {
        int wi = bid - 4096;
        int seg = wi >> 10;
        int i = (wi & 1023) * 256 + tid;
        const float* src = seg == 0 ? Wq : seg == 1 ? Wk : seg == 2 ? Wv : Wd;
        float sc = (seg == 0) ? SCALE_Q : 1.0f;
        float4 v = reinterpret_cast<const float4*>(src)[i];
        bf16x4 o = { (__bf16)(v.x * sc), (__bf16)(v.y * sc),
                     (__bf16)(v.z * sc), (__bf16)(v.w * sc) };
        reinterpret_cast<bf16x4*>(Wall)[(size_t)seg * 262144 + i] = o;
    } else {
        for (int i = tid; i < 3072; i += 256) {
            float v = (i < 1024) ? bq[i] * SCALE_Q
                    : (i < 2048) ? bk[i - 1024] : bv[i - 2048];
            bqkv[i] = v;
        }
    }
}

// ---------------------------------------------------------------- V transpose (LDS-tiled)
__global__ __launch_bounds__(256) void transpose_v(const __bf16* __restrict__ QKV,
                                                   __bf16* __restrict__ Vt) {
    __shared__ __bf16 t[64][66];
    const int st = blockIdx.x, bh = blockIdx.y;
    const int b = bh >> 4, h = bh & 15;
    const int tid = threadIdx.x;
    const int r = tid >> 3, c = tid & 7;
    const __bf16* src = QKV + (size_t)(b * SEQL + st * 64) * QKVLD + 2048 + h * 64;
    *(int4*)&t[r][c * 8]      = *(const int4*)(src + (size_t)r * QKVLD + c * 8);
    *(int4*)&t[r + 32][c * 8] = *(const int4*)(src + (size_t)(r + 32) * QKVLD + c * 8);
    __syncthreads();
    __bf16* dst = Vt + (size_t)bh * DH * SEQL + st * 64;
    const int d = tid >> 3;
    __bf16 tmp0[8], tmp1[8];
#pragma unroll
    for (int j = 0; j < 8; ++j) {
        tmp0[j] = t[c * 8 + j][d];
        tmp1[j] = t[c * 8 + j][d + 32];
    }
    *(int4*)(dst + (size_t)d * SEQL + c * 8)        = *(int4*)tmp0;
    *(int4*)(dst + (size_t)(d + 32) * SEQL + c * 8) = *(int4*)tmp1;
}

// ---------------------------------------------------------------- fused QKV GEMM (R11/R13: 128^2, 3-slot, vmcnt(4))
__global__ __launch_bounds__(256) void gemm_qkv(const __bf16* __restrict__ A,
                                                const __bf16* __restrict__ Bw,
                                                const float* __restrict__ bias,
                                                __bf16* __restrict__ C) {
    __shared__ __bf16 As[3][128 * 32];
    __shared__ __bf16 Bs[3][128 * 32];
    const int K = 1024, N = QKVLD;

    int bid = blockIdx.x;                       // 768 blocks
    int swz = (bid & 7) * 96 + (bid >> 3);      // XCD-chunked (768 % 8 == 0)
    const int bm = (swz & 31) * 128;
    const int bn = (swz >> 5) * 128;

    const int tid = threadIdx.x;
    const int w = tid >> 6, l = tid & 63, g = l >> 4, lc = l & 15;
    const int wr = (w >> 1) * 64, wc = (w & 1) * 64;
    const int row = tid >> 2, ch = tid & 3;

    const __bf16* Ap = A  + (size_t)(bm + row) * K + ch * 8;
    const __bf16* Bp = Bw + (size_t)(bn + row) * K + ch * 8;

    auto gstage = [&](int kt, int slot) {
        gload16(Ap + kt,                   &As[slot][w * 512]);
        gload16(Ap + kt + (size_t)64 * K,  &As[slot][2048 + w * 512]);
        gload16(Bp + kt,                   &Bs[slot][w * 512]);
        gload16(Bp + kt + (size_t)64 * K,  &Bs[slot][2048 + w * 512]);
    };

    f32x4 acc[4][4];
    const f32x4 z4 = {0.f, 0.f, 0.f, 0.f};
#pragma unroll
    for (int i = 0; i < 4; ++i)
#pragma unroll
        for (int j = 0; j < 4; ++j) acc[i][j] = z4;

    gstage(0, 0);
    gstage(32, 1);

    for (int kt = 0, it = 0; kt < K; kt += 32, ++it) {
        barrier_vm4();
        if (kt + 64 < K) gstage(kt + 64, (it + 2) % 3);

        const __bf16* Asl = &As[it % 3][0];
        const __bf16* Bsl = &Bs[it % 3][0];
        bf16x8 af[4], bfr[4];
#pragma unroll
        for (int i = 0; i < 4; ++i)
            af[i] = *(const bf16x8*)&Asl[(wr + i * 16 + lc) * 32 + g * 8];
#pragma unroll
        for (int j = 0; j < 4; ++j)
            bfr[j] = *(const bf16x8*)&Bsl[(wc + j * 16 + lc) * 32 + g * 8];
        __builtin_amdgcn_s_setprio(1);
#pragma unroll
        for (int i = 0; i < 4; ++i)
#pragma unroll
            for (int j = 0; j < 4; ++j)
                acc[i][j] = __builtin_amdgcn_mfma_f32_16x16x32_bf16(af[i], bfr[j], acc[i][j], 0, 0, 0);
        __builtin_amdgcn_s_setprio(0);
    }

#pragma unroll
    for (int i = 0; i < 4; ++i) {
        int r0 = bm + wr + i * 16 + g * 4;
#pragma unroll
        for (int j = 0; j < 4; ++j) {
            int c = bn + wc + j * 16 + lc;
            float bb = bias[c];
#pragma unroll
            for (int r = 0; r < 4; ++r)
                C[(size_t)(r0 + r) * N + c] = (__bf16)(acc[i][j][r] + bb);
        }
    }
}

// ---------------------------------------------------------------- out GEMM (R13: 64x128 tile + 3-slot vmcnt(3))
__global__ __launch_bounds__(256) void gemm_out(const __bf16* __restrict__ A,
                                                const __bf16* __restrict__ Bw,
                                                const float* __restrict__ bias,
                                                float* __restrict__ Cout) {
    __shared__ __bf16 As[3][64 * 32];
    __shared__ __bf16 Bs[3][128 * 32];
    const int K = 1024, N = 1024;

    int bid = blockIdx.x;                       // 512 blocks
    int swz = (bid & 7) * 64 + (bid >> 3);      // XCD-chunked
    const int bm = (swz & 63) * 64;
    const int bn = (swz >> 6) * 128;

    const int tid = threadIdx.x;
    const int w = tid >> 6, l = tid & 63, g = l >> 4, lc = l & 15;
    const int wr = (w >> 1) * 32, wc = (w & 1) * 64;
    const int row = tid >> 2, ch = tid & 3;

    const __bf16* Ap = A  + (size_t)(bm + row) * K + ch * 8;
    const __bf16* Bp = Bw + (size_t)(bn + row) * K + ch * 8;

    auto gstage = [&](int kt, int slot) {
        gload16(Ap + kt,                   &As[slot][w * 512]);
        gload16(Bp + kt,                   &Bs[slot][w * 512]);
        gload16(Bp + kt + (size_t)64 * K,  &Bs[slot][2048 + w * 512]);
    };

    f32x4 acc[2][4];
    const f32x4 z4 = {0.f, 0.f, 0.f, 0.f};
#pragma unroll
    for (int i = 0; i < 2; ++i)
#pragma unroll
        for (int j = 0; j < 4; ++j) acc[i][j] = z4;

    gstage(0, 0);
    gstage(32, 1);

    for (int kt = 0, it = 0; kt < K; kt += 32, ++it) {
        barrier_vm3();
        if (kt + 64 < K) gstage(kt + 64, (it + 2) % 3);

        const __bf16* Asl = &As[it % 3][0];
        const __bf16* Bsl = &Bs[it % 3][0];
        bf16x8 af[2], bfr[4];
#pragma unroll
        for (int i = 0; i < 2; ++i)
            af[i] = *(const bf16x8*)&Asl[(wr + i * 16 + lc) * 32 + g * 8];
#pragma unroll
        for (int j = 0; j < 4; ++j)
            bfr[j] = *(const bf16x8*)&Bsl[(wc + j * 16 + lc) * 32 + g * 8];
        __builtin_amdgcn_s_setprio(1);
#pragma unroll
        for (int i = 0; i < 2; ++i)
#pragma unroll
            for (int j = 0; j < 4; ++j)
                acc[i][j] = __builtin_amdgcn_mfma_f32_16x16x32_bf16(af[i], bfr[j], acc[i][j], 0, 0, 0);
        __builtin_amdgcn_s_setprio(0);
    }

#pragma unroll
    for (int i = 0; i < 2; ++i) {
        int r0 = bm + wr + i * 16 + g * 4;
#pragma unroll
        for (int j = 0; j < 4; ++j) {
            int c = bn + wc + j * 16 + lc;
            float bb = bias[c];
#pragma unroll
            for (int r = 0; r < 4; ++r)
                Cout[(size_t)(r0 + r) * N + c] = acc[i][j][r] + bb;
        }
    }
}

// ---------------------------------------------------------------- flash attention, split-K=2
// R13 inner loop; 512 blocks (split, bh, qt) x 8 waves x 32 q; k-span 1024 = 8 periods.
// 2-slot buffers (64 KB LDS) -> 2 blocks/CU = 4 waves/SIMD. Unnormalized partial O
// (bf16) + per-q l (f32); max-free log2 softmax makes the merge exact: (O0+O1)/(l0+l1).
__global__ __launch_bounds__(512) void attn_kernel(const __bf16* __restrict__ QKV,
                                                   const __bf16* __restrict__ Vt,
                                                   __bf16* __restrict__ P0,
                                                   __bf16* __restrict__ P1,
                                                   float* __restrict__ L) {
    __shared__ __bf16 k_lds[2][128][64];
    __shared__ __bf16 v_lds[2][64][128];

    const int tid = threadIdx.x;
    const int w  = tid >> 6;               // 0..7
    const int l  = tid & 63;
    const int ql = l & 31;
    const int lh = l >> 5;

    int bid = blockIdx.x;                       // 512 blocks
    int swz = (bid & 7) * 64 + (bid >> 3);      // XCD-chunked (512 % 8 == 0, bijective)
    const int split = (swz >> 8) & 1;
    const int bh = (swz >> 3) & 31;
    const int qt = swz & 7;
    const int b = bh >> 4, hd = bh & 15;
    const int qw = qt * 256 + w * 32;
    const int koff = split * 1024;

    const __bf16* Qg = QKV + (size_t)b * SEQL * QKVLD + hd * DH;
    const __bf16* Kg = Qg + 1024;
    const __bf16* Vg = Vt + (size_t)bh * DH * SEQL;
    __bf16* Pg = split ? P1 : P0;

    bf16x8 qf[4];
    {
        const __bf16* qp = Qg + (size_t)(qw + ql) * QKVLD + lh * 8;
#pragma unroll
        for (int c = 0; c < 4; ++c) qf[c] = *(const bf16x8*)(qp + c * 16);
    }

    const int sr   = l >> 3;
    const int gcol = ((l & 7) ^ sr) * 8;
    const int vr  = l >> 4;
    const int vch = l & 15;
    auto stage = [&](int kb, int slot) {
        gload16(Kg + (size_t)(kb + w * 8 + sr) * QKVLD + gcol,      &k_lds[slot][w * 8][0]);
        gload16(Kg + (size_t)(kb + 64 + w * 8 + sr) * QKVLD + gcol, &k_lds[slot][64 + w * 8][0]);
        int dr0 = w * 4 + vr;
        int dr1 = 32 + w * 4 + vr;
        gload16(Vg + (size_t)dr0 * SEQL + kb + (vch ^ (dr0 & 7)) * 8, &v_lds[slot][w * 4][0]);
        gload16(Vg + (size_t)dr1 * SEQL + kb + (vch ^ (dr1 & 7)) * 8, &v_lds[slot][32 + w * 4][0]);
    };

    f32x16 o0, o1;
#pragma unroll
    for (int r = 0; r < 16; ++r) { o0[r] = 0.f; o1[r] = 0.f; }
    float l8[8];
#pragma unroll
    for (int r = 0; r < 8; ++r) l8[r] = 0.f;

    f32x16 zc;
#pragma unroll
    for (int r = 0; r < 16; ++r) zc[r] = 0.f;

    const int NT = 1024 / 128;        // 8 barrier periods
    const int rsw = (ql & 7) << 3;

    stage(koff, 0);
    __syncthreads();

    for (int kt = 0; kt < NT; ++kt) {
        const int buf = kt & 1;
        const int kb = koff + kt * 128;

        if (kt + 1 < NT) stage(kb + 128, buf ^ 1);   // loads fly across this period

#pragma unroll
        for (int sub = 0; sub < 2; ++sub) {
            const int kbs = kb + sub * 64;
            const int ro  = sub * 64;

            f32x16 sA, sB;
            __builtin_amdgcn_s_setprio(1);
            {
                bf16x8 k0 = *(const bf16x8*)&k_lds[buf][ro + ql]     [(lh * 8) ^ rsw];
                bf16x8 k1 = *(const bf16x8*)&k_lds[buf][ro + 32 + ql][(lh * 8) ^ rsw];
                sA = __builtin_amdgcn_mfma_f32_32x32x16_bf16(k0, qf[0], zc, 0, 0, 0);
                sB = __builtin_amdgcn_mfma_f32_32x32x16_bf16(k1, qf[0], zc, 0, 0, 0);
            }
#pragma unroll
            for (int c = 1; c < 4; ++c) {
                bf16x8 k0 = *(const bf16x8*)&k_lds[buf][ro + ql]     [(c * 16 + lh * 8) ^ rsw];
                bf16x8 k1 = *(const bf16x8*)&k_lds[buf][ro + 32 + ql][(c * 16 + lh * 8) ^ rsw];
                sA = __builtin_amdgcn_mfma_f32_32x32x16_bf16(k0, qf[c], sA, 0, 0, 0);
                sB = __builtin_amdgcn_mfma_f32_32x32x16_bf16(k1, qf[c], sB, 0, 0, 0);
            }
            __builtin_amdgcn_s_setprio(0);

            if (kbs < qw + 32 && qw < kbs + 64) {
                const int qg = qw + ql;
#pragma unroll
                for (int i = 0; i < 16; ++i) {
                    int kg = kbs + (i & 3) + ((i >> 2) & 3) * 8 + lh * 4;
                    if (kg == qg)      sA[i] = -1e30f;
                    if (kg + 32 == qg) sB[i] = -1e30f;
                }
            }

#pragma unroll
            for (int i = 0; i < 16; ++i) sA[i] = exp2fast(sA[i]);
#pragma unroll
            for (int i = 0; i < 16; ++i) sB[i] = exp2fast(sB[i]);
#pragma unroll
            for (int i = 0; i < 8; ++i)
                l8[i] += (sA[i] + sA[i + 8]) + (sB[i] + sB[i + 8]);

            bf16x8 pa[4];
            {
                unsigned w0 = cvtpk(sA[0],  sA[1]);
                unsigned w1 = cvtpk(sA[2],  sA[3]);
                unsigned w2 = cvtpk(sA[4],  sA[5]);
                unsigned w3 = cvtpk(sA[6],  sA[7]);
                unsigned w4 = cvtpk(sA[8],  sA[9]);
                unsigned w5 = cvtpk(sA[10], sA[11]);
                unsigned w6 = cvtpk(sA[12], sA[13]);
                unsigned w7 = cvtpk(sA[14], sA[15]);
                pswap(w0, w2); pswap(w1, w3);
                pswap(w4, w6); pswap(w5, w7);
                uint4 lo4 = {w0, w1, w2, w3};
                uint4 hi4 = {w4, w5, w6, w7};
                pa[0] = *(bf16x8*)&lo4;
                pa[1] = *(bf16x8*)&hi4;
            }
            {
                unsigned w0 = cvtpk(sB[0],  sB[1]);
                unsigned w1 = cvtpk(sB[2],  sB[3]);
                unsigned w2 = cvtpk(sB[4],  sB[5]);
                unsigned w3 = cvtpk(sB[6],  sB[7]);
                unsigned w4 = cvtpk(sB[8],  sB[9]);
                unsigned w5 = cvtpk(sB[10], sB[11]);
                unsigned w6 = cvtpk(sB[12], sB[13]);
                unsigned w7 = cvtpk(sB[14], sB[15]);
                pswap(w0, w2); pswap(w1, w3);
                pswap(w4, w6); pswap(w5, w7);
                uint4 lo4 = {w0, w1, w2, w3};
                uint4 hi4 = {w4, w5, w6, w7};
                pa[2] = *(bf16x8*)&lo4;
                pa[3] = *(bf16x8*)&hi4;
            }

            __builtin_amdgcn_s_setprio(1);
#pragma unroll
            for (int s = 0; s < 2; ++s)
#pragma unroll
                for (int sl = 0; sl < 2; ++sl) {
                    const int col = sub * 64 + s * 32 + sl * 16 + lh * 8;
                    bf16x8 v0 = *(const bf16x8*)&v_lds[buf][ql]     [col ^ rsw];
                    bf16x8 v1 = *(const bf16x8*)&v_lds[buf][32 + ql][col ^ rsw];
                    o0 = __builtin_amdgcn_mfma_f32_32x32x16_bf16(pa[s * 2 + sl], v0, o0, 0, 0, 0);
                    o1 = __builtin_amdgcn_mfma_f32_32x32x16_bf16(pa[s * 2 + sl], v1, o1, 0, 0, 0);
                }
            __builtin_amdgcn_s_setprio(0);
        }

        __syncthreads();   // drains vmcnt -> buf^1 staged; all waves done reading buf
    }

    // epilogue: unnormalized partial O + per-q l
    float l_r = ((l8[0] + l8[1]) + (l8[2] + l8[3]))
              + ((l8[4] + l8[5]) + (l8[6] + l8[7]));
    l_r += __shfl_xor(l_r, 32, 64);
    if (lh == 0) L[(size_t)split * 65536 + bh * 2048 + qw + ql] = l_r;
#pragma unroll
    for (int r = 0; r < 16; ++r) {
        int cr = (r & 3) + (r >> 2) * 8 + lh * 4;
        int qrow = qw + cr;
        __bf16* cp = Pg + (size_t)(b * SEQL + qrow) * HIDDEN + hd * DH + ql;
        cp[0]  = (__bf16)o0[r];
        cp[32] = (__bf16)o1[r];
    }
}

// ---------------------------------------------------------------- split merge (in-place over P0 == Ctx)
__global__ __launch_bounds__(256) void attn_merge(const __bf16* __restrict__ P1,
                                                  const float* __restrict__ L,
                                                  __bf16* __restrict__ Ctx) {
    int idx = blockIdx.x * 256 + threadIdx.x;    // 524288 chunks of 8 elems
    int e = idx * 8;
    int row = e >> 10, col = e & 1023;
    int q = row & (SEQL - 1), b = row >> 11, hd = col >> 6;
    size_t li = (size_t)(b * 16 + hd) * 2048 + q;
    float l0 = L[li];
    float l1 = L[65536 + li];
    float inv = 1.f / (l0 + l1);
    bf16x8 u0 = reinterpret_cast<const bf16x8*>(Ctx)[idx];
    bf16x8 u1 = reinterpret_cast<const bf16x8*>(P1)[idx];
    bf16x8 o;
#pragma unroll
    for (int j = 0; j < 8; ++j)
        o[j] = (__bf16)(((float)u0[j] + (float)u1[j]) * inv);
    reinterpret_cast<bf16x8*>(Ctx)[idx] = o;
}

// ---------------------------------------------------------------- launch
extern "C" void kernel_launch(void* const* d_in, const int* in_sizes, int n_in,
                              void* d_out, int out_size, void* d_ws, size_t ws_size,
                              hipStream_t stream) {
    const float* H  = (const float*)d_in[0];
    const float* Wq = (const float*)d_in[1];
    const float* bq = (const float*)d_in[2];
    const float* Wk = (const float*)d_in[3];
    const float* bk = (const float*)d_in[4];
    const float* Wv = (const float*)d_in[5];
    const float* bv = (const float*)d_in[6];
    const float* Wd = (const float*)d_in[7];
    const float* bd = (const float*)d_in[8];
    float* out = (float*)d_out;

    char* ws = (char*)d_ws;
    const size_t MB = 1024 * 1024;
    __bf16* Hb    = (__bf16*)(ws + 0 * MB);    // 8 MB (dead after QKV gemm)
    __bf16* Ctx   = (__bf16*)(ws + 0 * MB);    // split-0 partial, merged in place
    __bf16* Wqkvb = (__bf16*)(ws + 8 * MB);    // 6 MB [Wq*s | Wk | Wv]
    __bf16* Wdb   = (__bf16*)(ws + 14 * MB);   // 2 MB (contiguous after Wv)
    float*  bqkv  = (float*) (ws + 16 * MB);   // 12 KB
    __bf16* QKV   = (__bf16*)(ws + 17 * MB);   // 24 MB
    __bf16* Vtb   = (__bf16*)(ws + 41 * MB);   // 8 MB
    __bf16* P1    = (__bf16*)(ws + 49 * MB);   // 8 MB split-1 partial
    float*  L     = (float*) (ws + 57 * MB);   // 512 KB -> 58 MB total
    if (ws_size < 58 * MB) return;

    prep<<<8193, 256, 0, stream>>>(H, Wq, Wk, Wv, Wd, bq, bk, bv, Hb, Wqkvb, bqkv);

    gemm_qkv<<<768, 256, 0, stream>>>(Hb, Wqkvb, bqkv, QKV);

    transpose_v<<<dim3(32, 32), 256, 0, stream>>>(QKV, Vtb);

    attn_kernel<<<512, 512, 0, stream>>>(QKV, Vtb, Ctx, P1, L);
    attn_merge<<<2048, 256, 0, stream>>>(P1, L, Ctx);

    gemm_out<<<512, 256, 0, stream>>>(Ctx, Wdb, bd, out);
}

// Round 15
// 118.447 us; speedup vs baseline: 1.0606x; 1.0606x over previous
//
#include <hip/hip_runtime.h>
#include <hip/hip_bf16.h>
#include <stdint.h>

#define HIDDEN 1024
#define SEQL   2048
#define NB     2
#define NH     16
#define DH     64
#define MTOT   (NB * SEQL)   // 4096
#define QKVLD  3072          // fused QKV row stride
#define SCALE_Q 0.18033688011112042f   // 0.125 * log2(e)

typedef __bf16 bf16x8 __attribute__((ext_vector_type(8)));
typedef __bf16 bf16x4 __attribute__((ext_vector_type(4)));
typedef float  f32x4  __attribute__((ext_vector_type(4)));
typedef float  f32x16 __attribute__((ext_vector_type(16)));

__device__ __forceinline__ void gload16(const void* g, void* l) {
    __builtin_amdgcn_global_load_lds(
        (const __attribute__((address_space(1))) void*)g,
        (__attribute__((address_space(3))) void*)l, 16, 0, 0);
}
__device__ __forceinline__ float exp2fast(float x) {
    float r;
    asm("v_exp_f32 %0, %1" : "=v"(r) : "v"(x));
    return r;
}
__device__ __forceinline__ unsigned cvtpk(float lo, float hi) {
    unsigned r;
    asm("v_cvt_pk_bf16_f32 %0, %1, %2" : "=v"(r) : "v"(lo), "v"(hi));
    return r;
}
__device__ __forceinline__ void pswap(unsigned& a, unsigned& b) {
    asm volatile("v_permlane32_swap_b32 %0, %1" : "+v"(a), "+v"(b));
}
// counted-vmcnt barriers: oldest loads done, newer ones stay in flight (T4)
__device__ __forceinline__ void barrier_vm3() {
    asm volatile("s_waitcnt vmcnt(3)" ::: "memory");
    __builtin_amdgcn_s_barrier();
    asm volatile("" ::: "memory");
}
__device__ __forceinline__ void barrier_vm4() {
    asm volatile("s_waitcnt vmcnt(4)" ::: "memory");
    __builtin_amdgcn_s_barrier();
    asm volatile("" ::: "memory");
}

// ---------------------------------------------------------------- fused prep
__global__ void prep(const float* __restrict__ H,
                     const float* __restrict__ Wq, const float* __restrict__ Wk,
                     const float* __restrict__ Wv, const float* __restrict__ Wd,
                     const float* __restrict__ bq, const float* __restrict__ bk,
                     const float* __restrict__ bv,
                     __bf16* __restrict__ Hb, __bf16* __restrict__ Wall,
                     float* __restrict__ bqkv) {
    const int bid = blockIdx.x, tid = threadIdx.x;
    if (bid < 4096) {
        int i = bid * 256 + tid;
        float4 v = reinterpret_cast<const float4*>(H)[i];
        bf16x4 o = { (__bf16)v.x, (__bf16)v.y, (__bf16)v.z, (__bf16)v.w };
        reinterpret_cast<bf16x4*>(Hb)[i] = o;
    } else if (bid < 8192) {
        int wi = bid - 4096;
        int seg = wi >> 10;
        int i = (wi & 1023) * 256 + tid;
        const float* src = seg == 0 ? Wq : seg == 1 ? Wk : seg == 2 ? Wv : Wd;
        float sc = (seg == 0) ? SCALE_Q : 1.0f;
        float4 v = reinterpret_cast<const float4*>(src)[i];
        bf16x4 o = { (__bf16)(v.x * sc), (__bf16)(v.y * sc),
                     (__bf16)(v.z * sc), (__bf16)(v.w * sc) };
        reinterpret_cast<bf16x4*>(Wall)[(size_t)seg * 262144 + i] = o;
    } else {
        for (int i = tid; i < 3072; i += 256) {
            float v = (i < 1024) ? bq[i] * SCALE_Q
                    : (i < 2048) ? bk[i - 1024] : bv[i - 2048];
            bqkv[i] = v;
        }
    }
}

// ---------------------------------------------------------------- V transpose (LDS-tiled)
__global__ __launch_bounds__(256) void transpose_v(const __bf16* __restrict__ QKV,
                                                   __bf16* __restrict__ Vt) {
    __shared__ __bf16 t[64][66];
    const int st = blockIdx.x, bh = blockIdx.y;
    const int b = bh >> 4, h = bh & 15;
    const int tid = threadIdx.x;
    const int r = tid >> 3, c = tid & 7;
    const __bf16* src = QKV + (size_t)(b * SEQL + st * 64) * QKVLD + 2048 + h * 64;
    *(int4*)&t[r][c * 8]      = *(const int4*)(src + (size_t)r * QKVLD + c * 8);
    *(int4*)&t[r + 32][c * 8] = *(const int4*)(src + (size_t)(r + 32) * QKVLD + c * 8);
    __syncthreads();
    __bf16* dst = Vt + (size_t)bh * DH * SEQL + st * 64;
    const int d = tid >> 3;
    __bf16 tmp0[8], tmp1[8];
#pragma unroll
    for (int j = 0; j < 8; ++j) {
        tmp0[j] = t[c * 8 + j][d];
        tmp1[j] = t[c * 8 + j][d + 32];
    }
    *(int4*)(dst + (size_t)d * SEQL + c * 8)        = *(int4*)tmp0;
    *(int4*)(dst + (size_t)(d + 32) * SEQL + c * 8) = *(int4*)tmp1;
}

// ---------------------------------------------------------------- fused QKV GEMM (R11: m97 + T4 counted-vmcnt, 3-slot, 128^2)
__global__ __launch_bounds__(256) void gemm_qkv(const __bf16* __restrict__ A,
                                                const __bf16* __restrict__ Bw,
                                                const float* __restrict__ bias,
                                                __bf16* __restrict__ C) {
    __shared__ __bf16 As[3][128 * 32];
    __shared__ __bf16 Bs[3][128 * 32];
    const int K = 1024, N = QKVLD;

    int bid = blockIdx.x;                       // 768 blocks
    int swz = (bid & 7) * 96 + (bid >> 3);      // XCD-chunked (768 % 8 == 0)
    const int bm = (swz & 31) * 128;
    const int bn = (swz >> 5) * 128;

    const int tid = threadIdx.x;
    const int w = tid >> 6, l = tid & 63, g = l >> 4, lc = l & 15;
    const int wr = (w >> 1) * 64, wc = (w & 1) * 64;
    const int row = tid >> 2, ch = tid & 3;

    const __bf16* Ap = A  + (size_t)(bm + row) * K + ch * 8;
    const __bf16* Bp = Bw + (size_t)(bn + row) * K + ch * 8;

    auto gstage = [&](int kt, int slot) {
        gload16(Ap + kt,                   &As[slot][w * 512]);
        gload16(Ap + kt + (size_t)64 * K,  &As[slot][2048 + w * 512]);
        gload16(Bp + kt,                   &Bs[slot][w * 512]);
        gload16(Bp + kt + (size_t)64 * K,  &Bs[slot][2048 + w * 512]);
    };

    f32x4 acc[4][4];
    const f32x4 z4 = {0.f, 0.f, 0.f, 0.f};
#pragma unroll
    for (int i = 0; i < 4; ++i)
#pragma unroll
        for (int j = 0; j < 4; ++j) acc[i][j] = z4;

    gstage(0, 0);
    gstage(32, 1);

    for (int kt = 0, it = 0; kt < K; kt += 32, ++it) {
        barrier_vm4();                          // this slot's 4 gloads done; next 4 in flight
        if (kt + 64 < K) gstage(kt + 64, (it + 2) % 3);

        const __bf16* Asl = &As[it % 3][0];
        const __bf16* Bsl = &Bs[it % 3][0];
        bf16x8 af[4], bfr[4];
#pragma unroll
        for (int i = 0; i < 4; ++i)
            af[i] = *(const bf16x8*)&Asl[(wr + i * 16 + lc) * 32 + g * 8];
#pragma unroll
        for (int j = 0; j < 4; ++j)
            bfr[j] = *(const bf16x8*)&Bsl[(wc + j * 16 + lc) * 32 + g * 8];
        __builtin_amdgcn_s_setprio(1);
#pragma unroll
        for (int i = 0; i < 4; ++i)
#pragma unroll
            for (int j = 0; j < 4; ++j)
                acc[i][j] = __builtin_amdgcn_mfma_f32_16x16x32_bf16(af[i], bfr[j], acc[i][j], 0, 0, 0);
        __builtin_amdgcn_s_setprio(0);
    }

#pragma unroll
    for (int i = 0; i < 4; ++i) {
        int r0 = bm + wr + i * 16 + g * 4;
#pragma unroll
        for (int j = 0; j < 4; ++j) {
            int c = bn + wc + j * 16 + lc;
            float bb = bias[c];
#pragma unroll
            for (int r = 0; r < 4; ++r)
                C[(size_t)(r0 + r) * N + c] = (__bf16)(acc[i][j][r] + bb);
        }
    }
}

// ---------------------------------------------------------------- out GEMM (64x128 tile + 3-slot counted vmcnt)
__global__ __launch_bounds__(256) void gemm_out(const __bf16* __restrict__ A,
                                                const __bf16* __restrict__ Bw,
                                                const float* __restrict__ bias,
                                                float* __restrict__ Cout) {
    __shared__ __bf16 As[3][64 * 32];
    __shared__ __bf16 Bs[3][128 * 32];
    const int K = 1024, N = 1024;

    int bid = blockIdx.x;                       // 512 blocks
    int swz = (bid & 7) * 64 + (bid >> 3);      // XCD-chunked
    const int bm = (swz & 63) * 64;
    const int bn = (swz >> 6) * 128;

    const int tid = threadIdx.x;
    const int w = tid >> 6, l = tid & 63, g = l >> 4, lc = l & 15;
    const int wr = (w >> 1) * 32, wc = (w & 1) * 64;
    const int row = tid >> 2, ch = tid & 3;

    const __bf16* Ap = A  + (size_t)(bm + row) * K + ch * 8;
    const __bf16* Bp = Bw + (size_t)(bn + row) * K + ch * 8;

    auto gstage = [&](int kt, int slot) {
        gload16(Ap + kt,                   &As[slot][w * 512]);
        gload16(Bp + kt,                   &Bs[slot][w * 512]);
        gload16(Bp + kt + (size_t)64 * K,  &Bs[slot][2048 + w * 512]);
    };

    f32x4 acc[2][4];
    const f32x4 z4 = {0.f, 0.f, 0.f, 0.f};
#pragma unroll
    for (int i = 0; i < 2; ++i)
#pragma unroll
        for (int j = 0; j < 4; ++j) acc[i][j] = z4;

    gstage(0, 0);
    gstage(32, 1);

    for (int kt = 0, it = 0; kt < K; kt += 32, ++it) {
        barrier_vm3();                          // this slot's 3 gloads done; next 3 in flight
        if (kt + 64 < K) gstage(kt + 64, (it + 2) % 3);

        const __bf16* Asl = &As[it % 3][0];
        const __bf16* Bsl = &Bs[it % 3][0];
        bf16x8 af[2], bfr[4];
#pragma unroll
        for (int i = 0; i < 2; ++i)
            af[i] = *(const bf16x8*)&Asl[(wr + i * 16 + lc) * 32 + g * 8];
#pragma unroll
        for (int j = 0; j < 4; ++j)
            bfr[j] = *(const bf16x8*)&Bsl[(wc + j * 16 + lc) * 32 + g * 8];
        __builtin_amdgcn_s_setprio(1);
#pragma unroll
        for (int i = 0; i < 2; ++i)
#pragma unroll
            for (int j = 0; j < 4; ++j)
                acc[i][j] = __builtin_amdgcn_mfma_f32_16x16x32_bf16(af[i], bfr[j], acc[i][j], 0, 0, 0);
        __builtin_amdgcn_s_setprio(0);
    }

#pragma unroll
    for (int i = 0; i < 2; ++i) {
        int r0 = bm + wr + i * 16 + g * 4;
#pragma unroll
        for (int j = 0; j < 4; ++j) {
            int c = bn + wc + j * 16 + lc;
            float bb = bias[c];
#pragma unroll
            for (int r = 0; r < 4; ++r)
                Cout[(size_t)(r0 + r) * N + c] = acc[i][j][r] + bb;
        }
    }
}

// ---------------------------------------------------------------- flash attention (R11/R13 structure — best measured, 48.9 µs)
__global__ __launch_bounds__(512) void attn_kernel(const __bf16* __restrict__ QKV,
                                                   const __bf16* __restrict__ Vt,
                                                   __bf16* __restrict__ Ctx) {
    __shared__ __bf16 k_lds[3][128][64];
    __shared__ __bf16 v_lds[3][64][128];
    __shared__ float  bc[8][32];

    const int tid = threadIdx.x;
    const int w  = tid >> 6;
    const int l  = tid & 63;
    const int ql = l & 31;
    const int lh = l >> 5;

    int bid = blockIdx.x;                       // 256 blocks
    int swz = (bid & 7) * 32 + (bid >> 3);      // XCD-chunked
    const int qt = swz & 7, bh = swz >> 3;
    const int b = bh >> 4, hd = bh & 15;
    const int qw = qt * 256 + w * 32;

    const __bf16* Qg = QKV + (size_t)b * SEQL * QKVLD + hd * DH;
    const __bf16* Kg = Qg + 1024;
    const __bf16* Vg = Vt + (size_t)bh * DH * SEQL;

    bf16x8 qf[4];
    {
        const __bf16* qp = Qg + (size_t)(qw + ql) * QKVLD + lh * 8;
#pragma unroll
        for (int c = 0; c < 4; ++c) qf[c] = *(const bf16x8*)(qp + c * 16);
    }

    const int sr   = l >> 3;
    const int gcol = ((l & 7) ^ sr) * 8;
    const int vr  = l >> 4;
    const int vch = l & 15;
    auto stage = [&](int kb, int slot) {
        gload16(Kg + (size_t)(kb + w * 8 + sr) * QKVLD + gcol,      &k_lds[slot][w * 8][0]);
        gload16(Kg + (size_t)(kb + 64 + w * 8 + sr) * QKVLD + gcol, &k_lds[slot][64 + w * 8][0]);
        int dr0 = w * 4 + vr;
        int dr1 = 32 + w * 4 + vr;
        gload16(Vg + (size_t)dr0 * SEQL + kb + (vch ^ (dr0 & 7)) * 8, &v_lds[slot][w * 4][0]);
        gload16(Vg + (size_t)dr1 * SEQL + kb + (vch ^ (dr1 & 7)) * 8, &v_lds[slot][32 + w * 4][0]);
    };

    f32x16 o0, o1;
#pragma unroll
    for (int r = 0; r < 16; ++r) { o0[r] = 0.f; o1[r] = 0.f; }
    float l8[8];
#pragma unroll
    for (int r = 0; r < 8; ++r) l8[r] = 0.f;

    f32x16 zc;
#pragma unroll
    for (int r = 0; r < 16; ++r) zc[r] = 0.f;

    const int NT = SEQL / 128;
    const int rsw = (ql & 7) << 3;

    stage(0, 0);
    stage(128, 1);

    for (int kt = 0; kt < NT; ++kt) {
        barrier_vm4();
        if (kt + 2 < NT) stage((kt + 2) * 128, (kt + 2) % 3);

        const int buf = kt % 3;
        const int kb = kt * 128;

#pragma unroll
        for (int sub = 0; sub < 2; ++sub) {
            const int kbs = kb + sub * 64;
            const int ro  = sub * 64;

            f32x16 sA, sB;
            __builtin_amdgcn_s_setprio(1);
            {
                bf16x8 k0 = *(const bf16x8*)&k_lds[buf][ro + ql]     [(lh * 8) ^ rsw];
                bf16x8 k1 = *(const bf16x8*)&k_lds[buf][ro + 32 + ql][(lh * 8) ^ rsw];
                sA = __builtin_amdgcn_mfma_f32_32x32x16_bf16(k0, qf[0], zc, 0, 0, 0);
                sB = __builtin_amdgcn_mfma_f32_32x32x16_bf16(k1, qf[0], zc, 0, 0, 0);
            }
#pragma unroll
            for (int c = 1; c < 4; ++c) {
                bf16x8 k0 = *(const bf16x8*)&k_lds[buf][ro + ql]     [(c * 16 + lh * 8) ^ rsw];
                bf16x8 k1 = *(const bf16x8*)&k_lds[buf][ro + 32 + ql][(c * 16 + lh * 8) ^ rsw];
                sA = __builtin_amdgcn_mfma_f32_32x32x16_bf16(k0, qf[c], sA, 0, 0, 0);
                sB = __builtin_amdgcn_mfma_f32_32x32x16_bf16(k1, qf[c], sB, 0, 0, 0);
            }
            __builtin_amdgcn_s_setprio(0);

            if (kbs < qw + 32 && qw < kbs + 64) {
                const int qg = qw + ql;
#pragma unroll
                for (int i = 0; i < 16; ++i) {
                    int kg = kbs + (i & 3) + ((i >> 2) & 3) * 8 + lh * 4;
                    if (kg == qg)      sA[i] = -1e30f;
                    if (kg + 32 == qg) sB[i] = -1e30f;
                }
            }

#pragma unroll
            for (int i = 0; i < 16; ++i) sA[i] = exp2fast(sA[i]);
#pragma unroll
            for (int i = 0; i < 16; ++i) sB[i] = exp2fast(sB[i]);
#pragma unroll
            for (int i = 0; i < 8; ++i)
                l8[i] += (sA[i] + sA[i + 8]) + (sB[i] + sB[i + 8]);

            bf16x8 pa[4];
            {
                unsigned w0 = cvtpk(sA[0],  sA[1]);
                unsigned w1 = cvtpk(sA[2],  sA[3]);
                unsigned w2 = cvtpk(sA[4],  sA[5]);
                unsigned w3 = cvtpk(sA[6],  sA[7]);
                unsigned w4 = cvtpk(sA[8],  sA[9]);
                unsigned w5 = cvtpk(sA[10], sA[11]);
                unsigned w6 = cvtpk(sA[12], sA[13]);
                unsigned w7 = cvtpk(sA[14], sA[15]);
                pswap(w0, w2); pswap(w1, w3);
                pswap(w4, w6); pswap(w5, w7);
                uint4 lo4 = {w0, w1, w2, w3};
                uint4 hi4 = {w4, w5, w6, w7};
                pa[0] = *(bf16x8*)&lo4;
                pa[1] = *(bf16x8*)&hi4;
            }
            {
                unsigned w0 = cvtpk(sB[0],  sB[1]);
                unsigned w1 = cvtpk(sB[2],  sB[3]);
                unsigned w2 = cvtpk(sB[4],  sB[5]);
                unsigned w3 = cvtpk(sB[6],  sB[7]);
                unsigned w4 = cvtpk(sB[8],  sB[9]);
                unsigned w5 = cvtpk(sB[10], sB[11]);
                unsigned w6 = cvtpk(sB[12], sB[13]);
                unsigned w7 = cvtpk(sB[14], sB[15]);
                pswap(w0, w2); pswap(w1, w3);
                pswap(w4, w6); pswap(w5, w7);
                uint4 lo4 = {w0, w1, w2, w3};
                uint4 hi4 = {w4, w5, w6, w7};
                pa[2] = *(bf16x8*)&lo4;
                pa[3] = *(bf16x8*)&hi4;
            }

            __builtin_amdgcn_s_setprio(1);
#pragma unroll
            for (int s = 0; s < 2; ++s)
#pragma unroll
                for (int sl = 0; sl < 2; ++sl) {
                    const int col = sub * 64 + s * 32 + sl * 16 + lh * 8;
                    bf16x8 v0 = *(const bf16x8*)&v_lds[buf][ql]     [col ^ rsw];
                    bf16x8 v1 = *(const bf16x8*)&v_lds[buf][32 + ql][col ^ rsw];
                    o0 = __builtin_amdgcn_mfma_f32_32x32x16_bf16(pa[s * 2 + sl], v0, o0, 0, 0, 0);
                    o1 = __builtin_amdgcn_mfma_f32_32x32x16_bf16(pa[s * 2 + sl], v1, o1, 0, 0, 0);
                }
            __builtin_amdgcn_s_setprio(0);
        }
    }

    float l_r = ((l8[0] + l8[1]) + (l8[2] + l8[3]))
              + ((l8[4] + l8[5]) + (l8[6] + l8[7]));
    l_r += __shfl_xor(l_r, 32, 64);
    if (lh == 0) bc[w][ql] = 1.f / l_r;
    asm volatile("s_waitcnt lgkmcnt(0)" ::: "memory");
    __builtin_amdgcn_wave_barrier();
#pragma unroll
    for (int r = 0; r < 16; ++r) {
        int cr = (r & 3) + (r >> 2) * 8 + lh * 4;
        float iv = bc[w][cr];
        int qrow = qw + cr;
        __bf16* cp = Ctx + (size_t)(b * SEQL + qrow) * HIDDEN + hd * DH + ql;
        cp[0]  = (__bf16)(o0[r] * iv);
        cp[32] = (__bf16)(o1[r] * iv);
    }
}

// ---------------------------------------------------------------- launch
extern "C" void kernel_launch(void* const* d_in, const int* in_sizes, int n_in,
                              void* d_out, int out_size, void* d_ws, size_t ws_size,
                              hipStream_t stream) {
    const float* H  = (const float*)d_in[0];
    const float* Wq = (const float*)d_in[1];
    const float* bq = (const float*)d_in[2];
    const float* Wk = (const float*)d_in[3];
    const float* bk = (const float*)d_in[4];
    const float* Wv = (const float*)d_in[5];
    const float* bv = (const float*)d_in[6];
    const float* Wd = (const float*)d_in[7];
    const float* bd = (const float*)d_in[8];
    float* out = (float*)d_out;

    char* ws = (char*)d_ws;
    const size_t MB = 1024 * 1024;
    __bf16* Hb    = (__bf16*)(ws + 0 * MB);    // 8 MB (dead after QKV gemm)
    __bf16* Ctx   = (__bf16*)(ws + 0 * MB);    // aliases Hb
    __bf16* Wqkvb = (__bf16*)(ws + 8 * MB);    // 6 MB [Wq*s | Wk | Wv]
    __bf16* Wdb   = (__bf16*)(ws + 14 * MB);   // 2 MB (contiguous after Wv)
    float*  bqkv  = (float*) (ws + 16 * MB);   // 12 KB
    __bf16* QKV   = (__bf16*)(ws + 17 * MB);   // 24 MB
    __bf16* Vtb   = (__bf16*)(ws + 41 * MB);   // 8 MB -> 49 MB total
    if (ws_size < 49 * MB) return;

    prep<<<8193, 256, 0, stream>>>(H, Wq, Wk, Wv, Wd, bq, bk, bv, Hb, Wqkvb, bqkv);

    gemm_qkv<<<768, 256, 0, stream>>>(Hb, Wqkvb, bqkv, QKV);

    transpose_v<<<dim3(32, 32), 256, 0, stream>>>(QKV, Vtb);

    attn_kernel<<<256, 512, 0, stream>>>(QKV, Vtb, Ctx);

    gemm_out<<<512, 256, 0, stream>>>(Ctx, Wdb, bd, out);
}